// Round 8
// baseline (324.327 us; speedup 1.0000x reference)
//
#include <hip/hip_runtime.h>
#include <hip/hip_cooperative_groups.h>

namespace cg = cooperative_groups;

#define BATCH 2048
#define NTEACH 64

typedef __attribute__((ext_vector_type(8))) short short8;
typedef __attribute__((ext_vector_type(4))) float f32x4;

__device__ __forceinline__ unsigned short f2bf(float f) {
    unsigned u = __float_as_uint(f);
    u += 0x7FFFu + ((u >> 16) & 1u);          // round-to-nearest-even
    return (unsigned short)(u >> 16);
}

__device__ __forceinline__ short8 cvt8(float4 a, float4 b) {
    short8 r;
    r[0] = (short)f2bf(a.x); r[1] = (short)f2bf(a.y);
    r[2] = (short)f2bf(a.z); r[3] = (short)f2bf(a.w);
    r[4] = (short)f2bf(b.x); r[5] = (short)f2bf(b.y);
    r[6] = (short)f2bf(b.z); r[7] = (short)f2bf(b.w);
    return r;
}

// Block-wide (256 thr) scan of tidx for teacher t -> (start, count); optional
// stable original-index list into ord (LDS). Uniform result. Proven R5.
__device__ __forceinline__ int2 scan_teacher(const int* __restrict__ tidx,
                                             int t, int* ord) {
    __shared__ int ws_[4];
    const int tid = threadIdx.x;
    const int lane = tid & 63;
    const int wid = tid >> 6;
    int base = 0;
    int my_lt = 0;
#pragma unroll
    for (int r = 0; r < 8; ++r) {
        int i = r * 256 + tid;
        int v = tidx[i];
        bool f = (v == t);
        my_lt += (v < t) ? 1 : 0;
        unsigned long long b = __ballot(f);
        if (lane == 0) ws_[wid] = __builtin_popcountll(b);
        int below = __builtin_popcountll(b & ((1ull << lane) - 1ull));
        __syncthreads();
        int w0 = ws_[0], w1 = ws_[1], w2 = ws_[2], w3 = ws_[3];
        if (ord && f) {
            int wbase = (wid > 0 ? w0 : 0) + (wid > 1 ? w1 : 0) + (wid > 2 ? w2 : 0);
            ord[base + wbase + below] = i;
        }
        base += w0 + w1 + w2 + w3;
        __syncthreads();
    }
    for (int off = 32; off; off >>= 1) my_lt += __shfl_down(my_lt, off);
    if (lane == 0) ws_[wid] = my_lt;
    __syncthreads();
    int start = ws_[0] + ws_[1] + ws_[2] + ws_[3];
    __syncthreads();
    return make_int2(start, base);
}

// ======================= cooperative mega kernel ===========================
// Grid 512 x 256thr, __launch_bounds__(256,2): 2 blocks/CU needed — large
// margin so hipLaunchCooperativeKernel cannot be TooLarge. Each block owns
// teacher t = bx&63 for ALL phases: scan ONCE; (start,count) registers and
// LDS ord[] persist across grid.sync(). MFMA 16x16x32 bf16 layouts verified
// R2-R5: A row=lane&15, k=(lane>>4)*8+j; B col=lane&15; D col=lane&15,
// row=(lane>>4)*4+j.
__global__ __launch_bounds__(256, 2) void mega_kernel(
    const float* __restrict__ obs, const int* __restrict__ tidx,
    const float* __restrict__ w0, const float* __restrict__ b0,
    const float* __restrict__ w2, const float* __restrict__ b2,
    const float* __restrict__ w4, const float* __restrict__ b4,
    const float* __restrict__ w6, const float* __restrict__ b6,
    unsigned short* __restrict__ h0, unsigned short* __restrict__ h1,
    unsigned short* __restrict__ h2, float* __restrict__ out) {
    __shared__ int ord[BATCH];
    __shared__ f32x4 red[3][64];

    cg::grid_group grid = cg::this_grid();
    const int bx = blockIdx.x;
    const int t = bx & 63;
    const int q = bx >> 6;                    // 0..7
    const int lane = threadIdx.x & 63, wid = threadIdx.x >> 6;
    const int ln = lane & 15, kg = lane >> 4;

    int2 sc = scan_teacher(tidx, t, ord);     // once; reused by all phases
    const int start = sc.x, count = sc.y;

    // ============ phase 0: L0 obs(48)->h0(512), gather+elu ============
    if (count > 0) {
        const int nq = wid & 1, mq = wid >> 1;
        for (int nt = q; nt < 16; nt += 8) {
            const int n0 = nt * 32 + nq * 16;
            short8 bf[2];
            const float* wr = w0 + ((size_t)t * 512 + n0 + ln) * 48;
#pragma unroll
            for (int kt = 0; kt < 2; ++kt) {
                int kb = kt * 32 + kg * 8;
                short8 f8 = {0, 0, 0, 0, 0, 0, 0, 0};
                if (kb < 48)
                    f8 = cvt8(*(const float4*)(wr + kb), *(const float4*)(wr + kb + 4));
                bf[kt] = f8;
            }
            const float bias = b0[(size_t)t * 512 + n0 + ln];
            for (int r0 = mq * 16; r0 < count; r0 += 32) {
                int lr = r0 + ln;
                const float* xr = obs + (size_t)ord[lr < count ? lr : 0] * 48;
                short8 af[2];
#pragma unroll
                for (int kt = 0; kt < 2; ++kt) {
                    int kb = kt * 32 + kg * 8;
                    short8 f8 = {0, 0, 0, 0, 0, 0, 0, 0};
                    if (kb < 48)
                        f8 = cvt8(*(const float4*)(xr + kb), *(const float4*)(xr + kb + 4));
                    af[kt] = f8;
                }
                f32x4 acc = {0.f, 0.f, 0.f, 0.f};
                acc = __builtin_amdgcn_mfma_f32_16x16x32_bf16(af[0], bf[0], acc, 0, 0, 0);
                acc = __builtin_amdgcn_mfma_f32_16x16x32_bf16(af[1], bf[1], acc, 0, 0, 0);
#pragma unroll
                for (int j = 0; j < 4; ++j) {
                    int row = r0 + kg * 4 + j;
                    if (row < count) {
                        float v = acc[j] + bias;
                        v = v > 0.f ? v : expm1f(v);
                        h0[(size_t)(start + row) * 512 + n0 + ln] = f2bf(v);
                    }
                }
            }
        }
    }
    __threadfence();
    grid.sync();

    // ============ phase 1: L1 h0(512)->h1(256), elu; K4 wave split ============
    if (count > 0) {
        for (int nt = q; nt < 16; nt += 8) {
            const int n0 = nt * 16;
            const int kbase = wid * 128;
            short8 bf[4];
            const float* wr = w2 + ((size_t)t * 256 + n0 + ln) * 512 + kbase;
#pragma unroll
            for (int k8 = 0; k8 < 4; ++k8) {
                int kb = k8 * 32 + kg * 8;
                bf[k8] = cvt8(*(const float4*)(wr + kb), *(const float4*)(wr + kb + 4));
            }
            const float bias = b2[(size_t)t * 256 + n0 + ln];
            for (int r0 = 0; r0 < count; r0 += 16) {
                const unsigned short* xr =
                    h0 + (size_t)(start + r0 + ln) * 512 + kbase + kg * 8;
                f32x4 acc = {0.f, 0.f, 0.f, 0.f};
#pragma unroll
                for (int k8 = 0; k8 < 4; ++k8)
                    acc = __builtin_amdgcn_mfma_f32_16x16x32_bf16(
                        *(const short8*)(xr + k8 * 32), bf[k8], acc, 0, 0, 0);
                __syncthreads();
                if (wid > 0) red[wid - 1][lane] = acc;
                __syncthreads();
                if (wid == 0) {
#pragma unroll
                    for (int s = 0; s < 3; ++s) {
                        f32x4 r = red[s][lane];
                        acc[0] += r[0]; acc[1] += r[1]; acc[2] += r[2]; acc[3] += r[3];
                    }
#pragma unroll
                    for (int j = 0; j < 4; ++j) {
                        int row = r0 + kg * 4 + j;
                        if (row < count) {
                            float v = acc[j] + bias;
                            v = v > 0.f ? v : expm1f(v);
                            h1[(size_t)(start + row) * 256 + n0 + ln] = f2bf(v);
                        }
                    }
                }
            }
        }
    }
    __threadfence();
    grid.sync();

    // ============ phase 2: L2 h1(256)->h2(128), elu; K4 wave split ============
    if (count > 0) {
        const int n0 = q * 16;
        const int kbase = wid * 64;
        short8 bf[2];
        const float* wr = w4 + ((size_t)t * 128 + n0 + ln) * 256 + kbase;
#pragma unroll
        for (int k8 = 0; k8 < 2; ++k8) {
            int kb = k8 * 32 + kg * 8;
            bf[k8] = cvt8(*(const float4*)(wr + kb), *(const float4*)(wr + kb + 4));
        }
        const float bias = b4[(size_t)t * 128 + n0 + ln];
        for (int r0 = 0; r0 < count; r0 += 16) {
            const unsigned short* xr =
                h1 + (size_t)(start + r0 + ln) * 256 + kbase + kg * 8;
            f32x4 acc = {0.f, 0.f, 0.f, 0.f};
#pragma unroll
            for (int k8 = 0; k8 < 2; ++k8)
                acc = __builtin_amdgcn_mfma_f32_16x16x32_bf16(
                    *(const short8*)(xr + k8 * 32), bf[k8], acc, 0, 0, 0);
            __syncthreads();
            if (wid > 0) red[wid - 1][lane] = acc;
            __syncthreads();
            if (wid == 0) {
#pragma unroll
                for (int s = 0; s < 3; ++s) {
                    f32x4 r = red[s][lane];
                    acc[0] += r[0]; acc[1] += r[1]; acc[2] += r[2]; acc[3] += r[3];
                }
#pragma unroll
                for (int j = 0; j < 4; ++j) {
                    int row = r0 + kg * 4 + j;
                    if (row < count) {
                        float v = acc[j] + bias;
                        v = v > 0.f ? v : expm1f(v);
                        h2[(size_t)(start + row) * 128 + n0 + ln] = f2bf(v);
                    }
                }
            }
        }
    }
    __threadfence();
    grid.sync();

    // ============ phase 3: final h2(128)->out(12), tanh (bx<256) ============
    if (bx < 256 && count > 0) {
        const int mq = q;                      // 0..3
        short8 bf[4];
        const float* wr = w6 + ((size_t)t * 12 + (ln < 12 ? ln : 0)) * 128;
#pragma unroll
        for (int kt = 0; kt < 4; ++kt) {
            int kb = kt * 32 + kg * 8;
            bf[kt] = cvt8(*(const float4*)(wr + kb), *(const float4*)(wr + kb + 4));
        }
        const float bias = (ln < 12) ? b6[(size_t)t * 12 + ln] : 0.f;
        for (int g = mq * 4 + wid; g * 16 < count; g += 16) {
            const int r0 = g * 16;
            const unsigned short* xr = h2 + (size_t)(start + r0 + ln) * 128 + kg * 8;
            f32x4 acc = {0.f, 0.f, 0.f, 0.f};
#pragma unroll
            for (int kt = 0; kt < 4; ++kt)
                acc = __builtin_amdgcn_mfma_f32_16x16x32_bf16(
                    *(const short8*)(xr + kt * 32), bf[kt], acc, 0, 0, 0);
#pragma unroll
            for (int j = 0; j < 4; ++j) {
                int row = r0 + kg * 4 + j;
                if (ln < 12 && row < count)
                    out[(size_t)ord[row] * 12 + ln] = tanhf(acc[j] + bias);
            }
        }
    }
}

// ======================= fallback: proven R5 3-kernel path ==================
__global__ __launch_bounds__(256) void l0_kernel(const float* __restrict__ obs,
                                                 const int* __restrict__ tidx,
                                                 const float* __restrict__ w0,
                                                 const float* __restrict__ b0,
                                                 unsigned short* __restrict__ h0) {
    __shared__ int ord[BATCH];
    const int t = blockIdx.y;
    int2 sc = scan_teacher(tidx, t, ord);
    const int start = sc.x, count = sc.y;
    if (count == 0) return;
    const int lane = threadIdx.x & 63, wid = threadIdx.x >> 6;
    const int ln = lane & 15, kg = lane >> 4;
    const int nq = wid & 1, mq = wid >> 1;
    const int n0 = blockIdx.x * 32 + nq * 16;

    short8 bf[2];
    const float* wr = w0 + ((size_t)t * 512 + n0 + ln) * 48;
#pragma unroll
    for (int kt = 0; kt < 2; ++kt) {
        int kb = kt * 32 + kg * 8;
        short8 f8 = {0, 0, 0, 0, 0, 0, 0, 0};
        if (kb < 48) f8 = cvt8(*(const float4*)(wr + kb), *(const float4*)(wr + kb + 4));
        bf[kt] = f8;
    }
    const float bias = b0[(size_t)t * 512 + n0 + ln];

    for (int r0 = mq * 16; r0 < count; r0 += 32) {
        int lr = r0 + ln;
        const float* xr = obs + (size_t)ord[lr < count ? lr : 0] * 48;
        short8 af[2];
#pragma unroll
        for (int kt = 0; kt < 2; ++kt) {
            int kb = kt * 32 + kg * 8;
            short8 f8 = {0, 0, 0, 0, 0, 0, 0, 0};
            if (kb < 48) f8 = cvt8(*(const float4*)(xr + kb), *(const float4*)(xr + kb + 4));
            af[kt] = f8;
        }
        f32x4 acc = {0.f, 0.f, 0.f, 0.f};
        acc = __builtin_amdgcn_mfma_f32_16x16x32_bf16(af[0], bf[0], acc, 0, 0, 0);
        acc = __builtin_amdgcn_mfma_f32_16x16x32_bf16(af[1], bf[1], acc, 0, 0, 0);
#pragma unroll
        for (int j = 0; j < 4; ++j) {
            int row = r0 + kg * 4 + j;
            if (row < count) {
                float v = acc[j] + bias;
                v = v > 0.f ? v : expm1f(v);
                h0[(size_t)(start + row) * 512 + n0 + ln] = f2bf(v);
            }
        }
    }
}

__global__ __launch_bounds__(256) void l1_kernel(const unsigned short* __restrict__ h0,
                                                 const int* __restrict__ tidx,
                                                 const float* __restrict__ w2,
                                                 const float* __restrict__ b2,
                                                 unsigned short* __restrict__ h1) {
    __shared__ f32x4 red[2][64];
    const int t = blockIdx.y;
    int2 sc = scan_teacher(tidx, t, nullptr);
    const int start = sc.x, count = sc.y;
    if (count == 0) return;
    const int lane = threadIdx.x & 63, wid = threadIdx.x >> 6;
    const int ln = lane & 15, kg = lane >> 4;
    const int kq = wid & 1, nq = wid >> 1;
    const int n0 = blockIdx.x * 32 + nq * 16;
    const int kbase = kq * 256;

    short8 bf[8];
    const float* wr = w2 + ((size_t)t * 256 + n0 + ln) * 512 + kbase;
#pragma unroll
    for (int k8 = 0; k8 < 8; ++k8) {
        int kb = k8 * 32 + kg * 8;
        bf[k8] = cvt8(*(const float4*)(wr + kb), *(const float4*)(wr + kb + 4));
    }
    const float bias = b2[(size_t)t * 256 + n0 + ln];

    for (int r0 = 0; r0 < count; r0 += 16) {
        const unsigned short* xr = h0 + (size_t)(start + r0 + ln) * 512 + kbase + kg * 8;
        f32x4 acc = {0.f, 0.f, 0.f, 0.f};
#pragma unroll
        for (int k8 = 0; k8 < 8; ++k8)
            acc = __builtin_amdgcn_mfma_f32_16x16x32_bf16(
                *(const short8*)(xr + k8 * 32), bf[k8], acc, 0, 0, 0);
        __syncthreads();
        if (kq == 1) red[nq][lane] = acc;
        __syncthreads();
        if (kq == 0) {
            f32x4 r = red[nq][lane];
            acc[0] += r[0]; acc[1] += r[1]; acc[2] += r[2]; acc[3] += r[3];
#pragma unroll
            for (int j = 0; j < 4; ++j) {
                int row = r0 + kg * 4 + j;
                if (row < count) {
                    float v = acc[j] + bias;
                    v = v > 0.f ? v : expm1f(v);
                    h1[(size_t)(start + row) * 256 + n0 + ln] = f2bf(v);
                }
            }
        }
    }
}

__global__ __launch_bounds__(256) void l2f_kernel(const unsigned short* __restrict__ h1,
                                                  const int* __restrict__ tidx,
                                                  const float* __restrict__ w4,
                                                  const float* __restrict__ b4,
                                                  const float* __restrict__ w6,
                                                  const float* __restrict__ b6,
                                                  float* __restrict__ out) {
    __shared__ int ord[BATCH];
    __shared__ char h2b[4096];
    const int t = blockIdx.y;
    int2 sc = scan_teacher(tidx, t, ord);
    const int start = sc.x, count = sc.y;
    if ((int)blockIdx.x * 16 >= count) return;
    const int lane = threadIdx.x & 63, wid = threadIdx.x >> 6;
    const int ln = lane & 15, kg = lane >> 4;
    const int nq = wid;

    short8 bfA[2][8];
    float biasA[2];
#pragma unroll
    for (int sub = 0; sub < 2; ++sub) {
        const float* wr = w4 + ((size_t)t * 128 + nq * 32 + sub * 16 + ln) * 256;
#pragma unroll
        for (int k8 = 0; k8 < 8; ++k8) {
            int kb = k8 * 32 + kg * 8;
            bfA[sub][k8] = cvt8(*(const float4*)(wr + kb), *(const float4*)(wr + kb + 4));
        }
        biasA[sub] = b4[(size_t)t * 128 + nq * 32 + sub * 16 + ln];
    }
    short8 bf6[4];
    float bias6 = 0.f;
    if (wid == 0) {
        const float* wr = w6 + ((size_t)t * 12 + (ln < 12 ? ln : 0)) * 128;
#pragma unroll
        for (int kt = 0; kt < 4; ++kt) {
            int kb = kt * 32 + kg * 8;
            bf6[kt] = cvt8(*(const float4*)(wr + kb), *(const float4*)(wr + kb + 4));
        }
        if (ln < 12) bias6 = b6[(size_t)t * 12 + ln];
    }

    for (int mt = blockIdx.x; mt * 16 < count; mt += gridDim.x) {
        const int gr0 = start + mt * 16;
#pragma unroll
        for (int sub = 0; sub < 2; ++sub) {
            const unsigned short* xr = h1 + (size_t)(gr0 + ln) * 256 + kg * 8;
            f32x4 acc = {0.f, 0.f, 0.f, 0.f};
#pragma unroll
            for (int k8 = 0; k8 < 8; ++k8)
                acc = __builtin_amdgcn_mfma_f32_16x16x32_bf16(
                    *(const short8*)(xr + k8 * 32), bfA[sub][k8], acc, 0, 0, 0);
            int col = nq * 32 + sub * 16 + ln;
#pragma unroll
            for (int j = 0; j < 4; ++j) {
                int row = kg * 4 + j;
                float v = acc[j] + biasA[sub];
                v = v > 0.f ? v : expm1f(v);
                int byte = (row * 256 + col * 2) ^ ((row & 7) << 4);
                *(unsigned short*)(h2b + byte) = f2bf(v);
            }
        }
        __syncthreads();
        if (wid == 0) {
            f32x4 acc = {0.f, 0.f, 0.f, 0.f};
#pragma unroll
            for (int kt = 0; kt < 4; ++kt) {
                int byte = (ln * 256 + (kt * 32 + kg * 8) * 2) ^ ((ln & 7) << 4);
                acc = __builtin_amdgcn_mfma_f32_16x16x32_bf16(
                    *(const short8*)(h2b + byte), bf6[kt], acc, 0, 0, 0);
            }
#pragma unroll
            for (int j = 0; j < 4; ++j) {
                int row = mt * 16 + kg * 4 + j;
                if (ln < 12 && row < count)
                    out[(size_t)ord[row] * 12 + ln] = tanhf(acc[j] + bias6);
            }
        }
        __syncthreads();
    }
}

extern "C" void kernel_launch(void* const* d_in, const int* in_sizes, int n_in,
                              void* d_out, int out_size, void* d_ws, size_t ws_size,
                              hipStream_t stream) {
    const float* obs = (const float*)d_in[0];
    const int* tidx  = (const int*)d_in[1];
    const float* w0  = (const float*)d_in[2];
    const float* b0  = (const float*)d_in[3];
    const float* w2  = (const float*)d_in[4];
    const float* b2  = (const float*)d_in[5];
    const float* w4  = (const float*)d_in[6];
    const float* b4  = (const float*)d_in[7];
    const float* w6  = (const float*)d_in[8];
    const float* b6  = (const float*)d_in[9];
    float* out = (float*)d_out;

    // bf16 activations in sorted space; +16 rows slack so tail A-fragment
    // overreads stay in-bounds (slack rows finite garbage, never stored).
    const int ROWS = BATCH + 16;
    unsigned short* h0 = (unsigned short*)d_ws;           // ROWS*512
    unsigned short* h1 = h0 + (size_t)ROWS * 512;         // ROWS*256
    unsigned short* h2 = h1 + (size_t)ROWS * 256;         // ROWS*128

    void* args[] = {&obs, &tidx, &w0, &b0, &w2, &b2, &w4, &b4, &w6, &b6,
                    &h0, &h1, &h2, &out};
    hipError_t err = hipLaunchCooperativeKernel((const void*)mega_kernel,
                                                dim3(512), dim3(256), args, 0,
                                                stream);
    if (err != hipSuccess) {
        // deterministic fallback: proven R5 pipeline, identical output
        l0_kernel<<<dim3(16, NTEACH), 256, 0, stream>>>(obs, tidx, w0, b0, h0);
        l1_kernel<<<dim3(8, NTEACH), 256, 0, stream>>>(h0, tidx, w2, b2, h1);
        l2f_kernel<<<dim3(4, NTEACH), 256, 0, stream>>>(h1, tidx, w4, b4, w6, b6, out);
    }
}

// Round 9
// 45.542 us; speedup vs baseline: 7.1215x; 7.1215x over previous
//
#include <hip/hip_runtime.h>

#define BATCH 2048
#define NTEACH 64

typedef __attribute__((ext_vector_type(8))) short short8;
typedef __attribute__((ext_vector_type(4))) float f32x4;

__device__ __forceinline__ unsigned short f2bf(float f) {
    unsigned u = __float_as_uint(f);
    u += 0x7FFFu + ((u >> 16) & 1u);          // round-to-nearest-even
    return (unsigned short)(u >> 16);
}

__device__ __forceinline__ short8 cvt8(float4 a, float4 b) {
    short8 r;
    r[0] = (short)f2bf(a.x); r[1] = (short)f2bf(a.y);
    r[2] = (short)f2bf(a.z); r[3] = (short)f2bf(a.w);
    r[4] = (short)f2bf(b.x); r[5] = (short)f2bf(b.y);
    r[6] = (short)f2bf(b.z); r[7] = (short)f2bf(b.w);
    return r;
}

// Barrier-free per-wave scan: every wave independently computes the full
// stable ranking of teacher-t samples (4x redundant, ZERO __syncthreads).
// Returns (start, count), wave-uniform. If ord != nullptr (LDS), each wave
// writes ALL count entries (same values from all waves -> benign race; a
// wave's own reads are ordered by lgkmcnt).
__device__ __forceinline__ int2 wave_scan(const int* __restrict__ tidx,
                                          int t, int* ord) {
    const int lane = threadIdx.x & 63;
    int base = 0, lt = 0;
#pragma unroll
    for (int r = 0; r < 32; ++r) {
        int i = r * 64 + lane;
        int v = tidx[i];
        bool f = (v == t);
        lt += (v < t) ? 1 : 0;
        unsigned long long b = __ballot(f);
        if (ord && f) {
            int rank = base + __builtin_popcountll(b & ((1ull << lane) - 1ull));
            ord[rank] = i;
        }
        base += __builtin_popcountll(b);
    }
#pragma unroll
    for (int off = 32; off; off >>= 1) lt += __shfl_down(lt, off);
    lt = __shfl(lt, 0);
    return make_int2(lt, base);
}

// ---------- L0: obs(48) -> h0(512) bf16 sorted, gather + elu ----------
// grid (16, 64); waves = N2 x M2. Weight loads issued BEFORE the scan so HBM
// latency hides under it. Block (0,t) publishes offsets/order for l1/l2f.
// MFMA 16x16x32 bf16 (verified R2-R7): A row=lane&15, k=(lane>>4)*8+j;
// B col=lane&15; D col=lane&15, row=(lane>>4)*4+j.
__global__ __launch_bounds__(256) void l0_kernel(const float* __restrict__ obs,
                                                 const int* __restrict__ tidx,
                                                 const float* __restrict__ w0,
                                                 const float* __restrict__ b0,
                                                 int* __restrict__ offsets_g,
                                                 int* __restrict__ order_g,
                                                 unsigned short* __restrict__ h0) {
    __shared__ int ord[BATCH];
    const int t = blockIdx.y;
    const int lane = threadIdx.x & 63, wid = threadIdx.x >> 6;
    const int ln = lane & 15, kg = lane >> 4;
    const int nq = wid & 1, mq = wid >> 1;
    const int n0 = blockIdx.x * 32 + nq * 16;

    // ---- issue weight + bias loads first (clamped addresses, mask later) ----
    const float* wr = w0 + ((size_t)t * 512 + n0 + ln) * 48;
    bool wvalid[2];
    float4 wa[2], wb[2];
#pragma unroll
    for (int kt = 0; kt < 2; ++kt) {
        int kb = kt * 32 + kg * 8;
        wvalid[kt] = kb < 48;
        const float* p = wr + (wvalid[kt] ? kb : 0);
        wa[kt] = *(const float4*)p;
        wb[kt] = *(const float4*)(p + 4);
    }
    const float bias = b0[(size_t)t * 512 + n0 + ln];

    // ---- scan (no barriers) while loads are in flight ----
    int2 sc = wave_scan(tidx, t, ord);
    const int start = sc.x, count = sc.y;

    // ---- publish offsets/order once ----
    if (blockIdx.x == 0) {
        if (threadIdx.x == 0) {
            offsets_g[t] = start;
            if (t == 0) offsets_g[NTEACH] = BATCH;
        }
        for (int i = threadIdx.x; i < count; i += 256) order_g[start + i] = ord[i];
    }
    if (count == 0) return;

    short8 bf[2];
#pragma unroll
    for (int kt = 0; kt < 2; ++kt) {
        short8 z = {0, 0, 0, 0, 0, 0, 0, 0};
        bf[kt] = wvalid[kt] ? cvt8(wa[kt], wb[kt]) : z;
    }

    for (int r0 = mq * 16; r0 < count; r0 += 32) {
        int lr = r0 + ln;
        const float* xr = obs + (size_t)ord[lr < count ? lr : 0] * 48;
        short8 af[2];
#pragma unroll
        for (int kt = 0; kt < 2; ++kt) {
            int kb = kt * 32 + kg * 8;
            short8 f8 = {0, 0, 0, 0, 0, 0, 0, 0};
            if (kb < 48)
                f8 = cvt8(*(const float4*)(xr + kb), *(const float4*)(xr + kb + 4));
            af[kt] = f8;
        }
        f32x4 acc = {0.f, 0.f, 0.f, 0.f};
        acc = __builtin_amdgcn_mfma_f32_16x16x32_bf16(af[0], bf[0], acc, 0, 0, 0);
        acc = __builtin_amdgcn_mfma_f32_16x16x32_bf16(af[1], bf[1], acc, 0, 0, 0);
#pragma unroll
        for (int j = 0; j < 4; ++j) {
            int row = r0 + kg * 4 + j;
            if (row < count) {
                float v = acc[j] + bias;
                v = v > 0.f ? v : expm1f(v);
                h0[(size_t)(start + row) * 512 + n0 + ln] = f2bf(v);
            }
        }
    }
}

// ---------- L1: h0(512) -> h1(256), elu. grid (8,64); waves = N2 x M2 -------
// NO scan (reads offsets), NO K-split, NO LDS, NO barriers. Each wave holds
// the full K=512 B-fragment (16 short8, loaded in 4 groups of 8 dwordx4).
__global__ __launch_bounds__(256) void l1_kernel(const unsigned short* __restrict__ h0,
                                                 const int* __restrict__ offsets_g,
                                                 const float* __restrict__ w2,
                                                 const float* __restrict__ b2,
                                                 unsigned short* __restrict__ h1) {
    const int t = blockIdx.y;
    const int start = offsets_g[t];
    const int count = offsets_g[t + 1] - start;
    if (count == 0) return;
    const int lane = threadIdx.x & 63, wid = threadIdx.x >> 6;
    const int ln = lane & 15, kg = lane >> 4;
    const int nq = wid & 1, mq = wid >> 1;
    const int n0 = blockIdx.x * 32 + nq * 16;

    const float* wr = w2 + ((size_t)t * 256 + n0 + ln) * 512;
    const float bias = b2[(size_t)t * 256 + n0 + ln];
    short8 bf[16];
#pragma unroll
    for (int g = 0; g < 4; ++g) {
        float4 ta[4], tb[4];
#pragma unroll
        for (int u = 0; u < 4; ++u) {
            int kb = (g * 4 + u) * 32 + kg * 8;
            ta[u] = *(const float4*)(wr + kb);
            tb[u] = *(const float4*)(wr + kb + 4);
        }
#pragma unroll
        for (int u = 0; u < 4; ++u) bf[g * 4 + u] = cvt8(ta[u], tb[u]);
    }

    for (int r0 = mq * 16; r0 < count; r0 += 32) {
        const unsigned short* xr = h0 + (size_t)(start + r0 + ln) * 512 + kg * 8;
        f32x4 acc = {0.f, 0.f, 0.f, 0.f};
#pragma unroll
        for (int k8 = 0; k8 < 16; ++k8)
            acc = __builtin_amdgcn_mfma_f32_16x16x32_bf16(
                *(const short8*)(xr + k8 * 32), bf[k8], acc, 0, 0, 0);
#pragma unroll
        for (int j = 0; j < 4; ++j) {
            int row = r0 + kg * 4 + j;
            if (row < count) {
                float v = acc[j] + bias;
                v = v > 0.f ? v : expm1f(v);
                h1[(size_t)(start + row) * 256 + n0 + ln] = f2bf(v);
            }
        }
    }
}

// ---------- L2+final: h1(256) -> h2(128, LDS) -> out(12), tanh --------------
// grid (4, 64); NO scan (offsets + global order). 16-row chunk per iteration.
__global__ __launch_bounds__(256) void l2f_kernel(const unsigned short* __restrict__ h1,
                                                  const int* __restrict__ offsets_g,
                                                  const int* __restrict__ order_g,
                                                  const float* __restrict__ w4,
                                                  const float* __restrict__ b4,
                                                  const float* __restrict__ w6,
                                                  const float* __restrict__ b6,
                                                  float* __restrict__ out) {
    __shared__ char h2b[4096];            // 16 rows x 128 cols bf16, swizzled
    const int t = blockIdx.y;
    const int start = offsets_g[t];
    const int count = offsets_g[t + 1] - start;
    if ((int)blockIdx.x * 16 >= count) return;
    const int lane = threadIdx.x & 63, wid = threadIdx.x >> 6;
    const int ln = lane & 15, kg = lane >> 4;
    const int nq = wid;

    short8 bfA[2][8];
    float biasA[2];
#pragma unroll
    for (int sub = 0; sub < 2; ++sub) {
        const float* wr = w4 + ((size_t)t * 128 + nq * 32 + sub * 16 + ln) * 256;
#pragma unroll
        for (int g = 0; g < 2; ++g) {
            float4 ta[4], tb[4];
#pragma unroll
            for (int u = 0; u < 4; ++u) {
                int kb = (g * 4 + u) * 32 + kg * 8;
                ta[u] = *(const float4*)(wr + kb);
                tb[u] = *(const float4*)(wr + kb + 4);
            }
#pragma unroll
            for (int u = 0; u < 4; ++u) bfA[sub][g * 4 + u] = cvt8(ta[u], tb[u]);
        }
        biasA[sub] = b4[(size_t)t * 128 + nq * 32 + sub * 16 + ln];
    }
    short8 bf6[4];
    float bias6 = 0.f;
    if (wid == 0) {
        const float* wr = w6 + ((size_t)t * 12 + (ln < 12 ? ln : 0)) * 128;
#pragma unroll
        for (int kt = 0; kt < 4; ++kt) {
            int kb = kt * 32 + kg * 8;
            bf6[kt] = cvt8(*(const float4*)(wr + kb), *(const float4*)(wr + kb + 4));
        }
        if (ln < 12) bias6 = b6[(size_t)t * 12 + ln];
    }

    for (int mt = blockIdx.x; mt * 16 < count; mt += gridDim.x) {
        const int gr0 = start + mt * 16;
#pragma unroll
        for (int sub = 0; sub < 2; ++sub) {
            const unsigned short* xr = h1 + (size_t)(gr0 + ln) * 256 + kg * 8;
            f32x4 acc = {0.f, 0.f, 0.f, 0.f};
#pragma unroll
            for (int k8 = 0; k8 < 8; ++k8)
                acc = __builtin_amdgcn_mfma_f32_16x16x32_bf16(
                    *(const short8*)(xr + k8 * 32), bfA[sub][k8], acc, 0, 0, 0);
            int col = nq * 32 + sub * 16 + ln;
#pragma unroll
            for (int j = 0; j < 4; ++j) {
                int row = kg * 4 + j;             // sample within chunk
                float v = acc[j] + biasA[sub];
                v = v > 0.f ? v : expm1f(v);
                int byte = (row * 256 + col * 2) ^ ((row & 7) << 4);
                *(unsigned short*)(h2b + byte) = f2bf(v);
            }
        }
        __syncthreads();
        if (wid == 0) {
            f32x4 acc = {0.f, 0.f, 0.f, 0.f};
#pragma unroll
            for (int kt = 0; kt < 4; ++kt) {
                int byte = (ln * 256 + (kt * 32 + kg * 8) * 2) ^ ((ln & 7) << 4);
                acc = __builtin_amdgcn_mfma_f32_16x16x32_bf16(
                    *(const short8*)(h2b + byte), bf6[kt], acc, 0, 0, 0);
            }
#pragma unroll
            for (int j = 0; j < 4; ++j) {
                int row = mt * 16 + kg * 4 + j;
                if (ln < 12 && row < count)
                    out[(size_t)order_g[start + row] * 12 + ln] = tanhf(acc[j] + bias6);
            }
        }
        __syncthreads();
    }
}

extern "C" void kernel_launch(void* const* d_in, const int* in_sizes, int n_in,
                              void* d_out, int out_size, void* d_ws, size_t ws_size,
                              hipStream_t stream) {
    const float* obs = (const float*)d_in[0];
    const int* tidx  = (const int*)d_in[1];
    const float* w0  = (const float*)d_in[2];
    const float* b0  = (const float*)d_in[3];
    const float* w2  = (const float*)d_in[4];
    const float* b2  = (const float*)d_in[5];
    const float* w4  = (const float*)d_in[6];
    const float* b4  = (const float*)d_in[7];
    const float* w6  = (const float*)d_in[8];
    const float* b6  = (const float*)d_in[9];
    float* out = (float*)d_out;

    // ws: offsets (65 ints) | order (2048 ints) | h0 | h1. bf16 activations in
    // sorted space; +16 rows slack so tail A-fragment overreads stay in-bounds
    // (slack rows are finite garbage — 0xAA poison is a finite bf16 — and
    // their D rows are never stored).
    const int ROWS = BATCH + 16;
    char* ws = (char*)d_ws;
    int* offsets = (int*)ws;                              // 65 ints
    int* order   = (int*)(ws + 1024);                     // 2048 ints
    unsigned short* h0 = (unsigned short*)(ws + 16384);   // ROWS*512
    unsigned short* h1 = h0 + (size_t)ROWS * 512;         // ROWS*256

    l0_kernel<<<dim3(16, NTEACH), 256, 0, stream>>>(obs, tidx, w0, b0,
                                                    offsets, order, h0);
    l1_kernel<<<dim3(8, NTEACH), 256, 0, stream>>>(h0, offsets, w2, b2, h1);
    l2f_kernel<<<dim3(4, NTEACH), 256, 0, stream>>>(h1, offsets, order,
                                                    w4, b4, w6, b6, out);
}